// Round 7
// baseline (307.743 us; speedup 1.0000x reference)
//
#include <hip/hip_runtime.h>
#include <stdint.h>

#define NV 1024
#define EMB 64

typedef __attribute__((ext_vector_type(8))) short bf16x8;
typedef __attribute__((ext_vector_type(4))) float f32x4;

__device__ __forceinline__ unsigned short f2b(float f) {
  unsigned int u = __builtin_bit_cast(unsigned int, f);
  u += 0x7fffu + ((u >> 16) & 1u);   // RNE
  return (unsigned short)(u >> 16);
}
__device__ __forceinline__ float b2f(unsigned short s) {
  unsigned int u = ((unsigned int)s) << 16;
  return __builtin_bit_cast(float, u);
}

__device__ __forceinline__ void gll16(void* lds, const void* gsrc) {
  __builtin_amdgcn_global_load_lds(
      (const __attribute__((address_space(1))) unsigned int*)gsrc,
      (__attribute__((address_space(3))) unsigned int*)lds, 16, 0, 0);
}

// ---------------------------------------------------------------------------
// k_prep: deg row-sums, graph f32->bf16, w34 = W3@W4, emb1 = relu(base),
// written transposed embT[b][e][n]. grid 2048 (16-row tiles, batch->XCD
// swizzled), 256 threads, 6 blocks/CU. Wave-private rows (no serial shfl
// chain); deg via LDS transpose reduce. Block 0 also zeroes esum_ws.
// ---------------------------------------------------------------------------
__global__ __launch_bounds__(256, 6) void k_prep(
    const float* __restrict__ graph, const float* __restrict__ Xv,
    const float* __restrict__ W1, const float* __restrict__ W3,
    const float* __restrict__ W4,
    unsigned short* __restrict__ G16, float* __restrict__ degp,
    float* __restrict__ w34g, unsigned short* __restrict__ embT,
    float* __restrict__ esum_ws)
{
  __shared__ float w34s[EMB];
  __shared__ float partsT[64 * 16];            // [lane][rowslot]
  __shared__ float degw[16], xvw[16];
  __shared__ unsigned short ebT[EMB][18];      // [e][n] + pad
  const int tid = threadIdx.x;
  const int j = blockIdx.x;
  const int b = (j & 7) + 8 * (j >> 9);        // batch -> XCD b&7
  const int rt = (j >> 3) & 63;                // 16-row tile
  const int wv = tid >> 6, lane = tid & 63;

  if (j == 0) {                                 // zero esum (replaces memset)
    ((float4*)esum_ws)[tid] = float4{0.f, 0.f, 0.f, 0.f};
    ((float4*)esum_ws)[tid + 256] = float4{0.f, 0.f, 0.f, 0.f};
  }
  if (tid < EMB) {
    float s = 0.f;
    const float* w3r = W3 + tid * EMB;
#pragma unroll
    for (int k = 0; k < EMB; ++k) s += w3r[k] * W4[k];
    w34s[tid] = s;
    if (j == 0) w34g[tid] = s;
  }

  // each wave owns 4 rows; full-wave coalesced row read; convert+store G16
#pragma unroll 2
  for (int r = 0; r < 4; ++r) {
    const int slot = wv * 4 + r;
    const int row = rt * 16 + slot;
    const float4* gr = (const float4*)(graph + ((size_t)b * NV + row) * NV);
    float part = 0.f;
    ushort4 outp[4];
#pragma unroll
    for (int c = 0; c < 4; ++c) {
      float4 v = gr[c * 64 + lane];
      part += (v.x + v.y) + (v.z + v.w);
      outp[c].x = f2b(v.x); outp[c].y = f2b(v.y);
      outp[c].z = f2b(v.z); outp[c].w = f2b(v.w);
    }
    ushort4* g16r = (ushort4*)(G16 + ((size_t)b * NV + row) * NV);
#pragma unroll
    for (int c = 0; c < 4; ++c) g16r[c * 64 + lane] = outp[c];
    partsT[lane * 16 + slot] = part;
  }
  __syncthreads();
  if (tid < 16) {
    float s = 0.f;
#pragma unroll
    for (int l = 0; l < 64; ++l) s += partsT[l * 16 + tid];
    degw[tid] = s;
    xvw[tid] = Xv[b * NV + rt * 16 + tid];
    degp[b * NV + rt * 16 + tid] = s;
  }
  __syncthreads();
  // emb1[e][n] = relu(xv*W1[e] + deg*w34[e]) for the 16 local n's
  {
    const int e = tid >> 2, q = tid & 3;
    const float w1e = W1[e], w34e = w34s[e];
#pragma unroll
    for (int n = q * 4; n < q * 4 + 4; ++n)
      ebT[e][n] = f2b(fmaxf(xvw[n] * w1e + degw[n] * w34e, 0.f));
  }
  __syncthreads();
  {
    const int e = tid >> 2, q = tid & 3;
    *(ushort4*)(embT + ((size_t)(b * EMB + e)) * NV + rt * 16 + q * 4) =
        *(const ushort4*)(&ebT[e][q * 4]);
  }
}

// ---------------------------------------------------------------------------
// k_step: embout = relu(base + (G @ embin) @ W2^T), embT layout in/out.
// grid 1024 (32-row M-tiles), 256 threads = 4 waves (2m x 2n of 16x32).
// 4 independent blocks/CU (36KB LDS, launch_bounds(256,4)), depth-2 counted
// vmcnt. LAST=1 accumulates emb_sum into esum_ws.
// ---------------------------------------------------------------------------
template <int LAST>
__global__ __launch_bounds__(256, 4) void k_step(
    const unsigned short* __restrict__ G16,
    const unsigned short* __restrict__ embin,
    unsigned short* __restrict__ embout,
    const float* __restrict__ W2, const float* __restrict__ W1,
    const float* __restrict__ w34g, const float* __restrict__ Xv,
    const float* __restrict__ degp, float* __restrict__ esum_ws)
{
  __shared__ __align__(16) char ldsbuf[36864];   // 3 x [A 4K | B 8K]
  __shared__ float esl[EMB];
  const int tid = threadIdx.x;
  const int lane = tid & 63;
  const int wv = tid >> 6;
  const int j = blockIdx.x;
  const int b = (j & 7) + 8 * (j >> 8);          // batch -> XCD b&7
  const int mt = (j >> 3) & 31;                  // 32-row tile
  const int wm = wv >> 1, wn = wv & 1;
  const int l15 = lane & 15, l4 = lane >> 4;

  // W2 fragments + per-lane base factors
  bf16x8 w2f[2][2];
  float w1e[2], w34e[2];
#pragma unroll
  for (int e16 = 0; e16 < 2; ++e16) {
    const int eg = wn * 32 + e16 * 16 + l15;
    w1e[e16] = W1[eg];
    w34e[e16] = w34g[eg];
#pragma unroll
    for (int kk = 0; kk < 2; ++kk) {
      const float* src = W2 + eg * 64 + kk * 32 + l4 * 8;
      bf16x8 f;
#pragma unroll
      for (int jj = 0; jj < 8; ++jj) f[jj] = (short)f2b(src[jj]);
      w2f[e16][kk] = f;
    }
  }
  if (LAST && tid < EMB) esl[tid] = 0.f;

  f32x4 acc[2] = {};                   // wave's 16x32 output
  const size_t gbase = ((size_t)b * NV + mt * 32) * NV;
  const size_t ebase = (size_t)b * EMB * NV;

  // A: 1 gll16/thread (32x64 tile); B: 2 gll16/thread (64x64 tile)
  const int arow = tid >> 3;                       // 0..31
  const int agcg = (tid & 7) ^ (arow & 7);
  const size_t asrc = gbase + (size_t)arow * NV + agcg * 8;

  auto STAGE = [&](int bufi, int kt) {
    char* Ad = ldsbuf + bufi * 12288;
    char* Bd = Ad + 4096;
    gll16(Ad + tid * 16, G16 + asrc + kt * 64);
#pragma unroll
    for (int i = 0; i < 2; ++i) {
      const int cc = i * 256 + tid;
      const int er = cc >> 3, lcg = cc & 7;
      const int gcg = lcg ^ (er & 7);
      gll16(Bd + cc * 16, embin + ebase + (size_t)er * NV + kt * 64 + gcg * 8);
    }
  };

  STAGE(0, 0); STAGE(1, 1);
  for (int kt = 0; kt < 16; ++kt) {
    if (kt < 14) {
      STAGE((kt + 2) % 3, kt + 2);                      // 2 tiles in flight
      asm volatile("s_waitcnt vmcnt(6)" ::: "memory");  // tile kt landed
    } else if (kt == 14) {
      asm volatile("s_waitcnt vmcnt(3)" ::: "memory");
    } else {
      asm volatile("s_waitcnt vmcnt(0)" ::: "memory");
    }
    __builtin_amdgcn_s_barrier();
    asm volatile("" ::: "memory");
    const char* At = ldsbuf + (kt % 3) * 12288;
    const char* Bt = At + 4096;
#pragma unroll
    for (int kk = 0; kk < 2; ++kk) {
      const int gq = kk * 4 + l4;
      const int row = wm * 16 + l15;
      const bf16x8 af = *(const bf16x8*)(At + row * 128 + ((gq ^ (row & 7)) << 4));
#pragma unroll
      for (int n16 = 0; n16 < 2; ++n16) {
        const int er = wn * 32 + n16 * 16 + l15;
        const bf16x8 bfr = *(const bf16x8*)(Bt + er * 128 + ((gq ^ (er & 7)) << 4));
        acc[n16] = __builtin_amdgcn_mfma_f32_16x16x32_bf16(af, bfr, acc[n16], 0, 0, 0);
      }
    }
    asm volatile("" ::: "memory");
    __builtin_amdgcn_s_barrier();
  }

  // ---- epilogue: S (32x64) -> LDS swizzled bf16 in buf0-A, then S @ W2^T ----
  char* St = ldsbuf;
#pragma unroll
  for (int n16 = 0; n16 < 2; ++n16)
#pragma unroll
    for (int r = 0; r < 4; ++r) {
      const int m = wm * 16 + l4 * 4 + r;
      const int n = wn * 32 + n16 * 16 + l15;
      const int addr = m * 128 + (((n >> 3) ^ (m & 7)) << 4) + (n & 7) * 2;
      *(unsigned short*)(St + addr) = f2b(acc[n16][r]);
    }
  __syncthreads();

  f32x4 acc2[2] = {};
#pragma unroll
  for (int kk = 0; kk < 2; ++kk) {
    const int gq = kk * 4 + l4;
    const int row = wm * 16 + l15;
    const bf16x8 sa = *(const bf16x8*)(St + row * 128 + ((gq ^ (row & 7)) << 4));
#pragma unroll
    for (int e16 = 0; e16 < 2; ++e16)
      acc2[e16] = __builtin_amdgcn_mfma_f32_16x16x32_bf16(
          sa, w2f[e16][kk], acc2[e16], 0, 0, 0);
  }

  // + base, relu, write transposed bf16; LAST also accumulates emb_sum
  const int ml0 = wm * 16 + l4 * 4;
  const int m0 = mt * 32 + ml0;
  float xv4[4], dg4[4];
#pragma unroll
  for (int r = 0; r < 4; ++r) {
    xv4[r] = Xv[b * NV + m0 + r];
    dg4[r] = degp[b * NV + m0 + r];
  }
#pragma unroll
  for (int e16 = 0; e16 < 2; ++e16) {
    const int eg = wn * 32 + e16 * 16 + l15;
    ushort4 pk;
    unsigned short* pks = (unsigned short*)&pk;
    float evs = 0.f;
#pragma unroll
    for (int r = 0; r < 4; ++r) {
      const float bs = xv4[r] * w1e[e16] + dg4[r] * w34e[e16];
      const float val = fmaxf(acc2[e16][r] + bs, 0.f);
      pks[r] = f2b(val);
      evs += val;
    }
    *(ushort4*)(embout + ((size_t)(b * EMB + eg)) * NV + m0) = pk;
    if (LAST) atomicAdd(&esl[eg], evs);
  }
  if (LAST) {
    __syncthreads();
    if (tid < EMB) atomicAdd(&esum_ws[b * EMB + tid], esl[tid]);
  }
}

// ---------------------------------------------------------------------------
// k_out: out[b,n] = s6[b] + sum_e W5[64+e]*relu(W7 @ emb_v); s6 from esum_ws.
// grid 256 (128 vertices each), 256 threads (2 e-half groups x 128 v).
// ---------------------------------------------------------------------------
__global__ __launch_bounds__(256) void k_out(
    const unsigned short* __restrict__ embT, const float* __restrict__ W7,
    const float* __restrict__ W5, const float* __restrict__ W6,
    const float* __restrict__ esum_ws, float* __restrict__ out)
{
  __shared__ __align__(16) unsigned short et[EMB][128];
  __shared__ float redl[256];
  __shared__ float s6l;
  const int tid = threadIdx.x;
  const int b = blockIdx.x >> 3;
  const int n0 = (blockIdx.x & 7) * 128;
#pragma unroll
  for (int i = 0; i < 4; ++i) {
    const int c = i * 256 + tid;               // 1024 16B chunks
    const int k = c >> 4, off = (c & 15) * 8;
    *(uint4*)&et[k][off] =
        *(const uint4*)(embT + ((size_t)(b * EMB + k)) * NV + n0 + off);
  }
  if (tid < EMB) {
    const float* es = esum_ws + b * EMB;
    float v6 = 0.f;
    const float* w6r = W6 + tid * EMB;
#pragma unroll
    for (int k = 0; k < EMB; ++k) v6 += w6r[k] * es[k];
    float c = W5[tid] * fmaxf(v6, 0.f);
#pragma unroll
    for (int d = 1; d < 64; d <<= 1) c += __shfl_xor(c, d);
    if (tid == 0) s6l = c;
  }
  __syncthreads();
  const int v = tid & 127, eh = tid >> 7;      // wave-uniform e-half
  float ev[64];
#pragma unroll
  for (int k = 0; k < 64; ++k) ev[k] = b2f(et[k][v]);
  float sp = 0.f;
  for (int e = eh * 32; e < eh * 32 + 32; ++e) {
    const float* w7r = W7 + e * 64;            // wave-uniform -> scalar loads
    float a = 0.f;
#pragma unroll
    for (int k = 0; k < 64; ++k) a += ev[k] * w7r[k];
    sp += W5[64 + e] * fmaxf(a, 0.f);
  }
  redl[tid] = sp;
  __syncthreads();
  if (tid < 128)
    out[b * NV + n0 + tid] = s6l + redl[tid] + redl[tid + 128];
}

// ---------------------------------------------------------------------------
extern "C" void kernel_launch(void* const* d_in, const int* in_sizes, int n_in,
                              void* d_out, int out_size, void* d_ws, size_t ws_size,
                              hipStream_t stream) {
  const float* graph = (const float*)d_in[0];
  const float* Xv = (const float*)d_in[1];
  const float* W1 = (const float*)d_in[2];
  const float* W2 = (const float*)d_in[3];
  const float* W3 = (const float*)d_in[4];
  const float* W4 = (const float*)d_in[5];
  const float* W5 = (const float*)d_in[6];
  const float* W6 = (const float*)d_in[7];
  const float* W7 = (const float*)d_in[8];
  float* out = (float*)d_out;
  char* ws = (char*)d_ws;

  unsigned short* G16 = (unsigned short*)ws;                     // 64 MB
  unsigned short* embA = (unsigned short*)(ws + (64u << 20));    // 4 MB
  unsigned short* embB = (unsigned short*)(ws + (68u << 20));    // 4 MB
  float* degp = (float*)(ws + (72u << 20));                      // 128 KB
  float* w34g = (float*)(ws + (72u << 20) + (128u << 10));       // 256 B
  float* esum_ws = (float*)(ws + (72u << 20) + (130u << 10));    // 8 KB

  k_prep<<<2048, 256, 0, stream>>>(graph, Xv, W1, W3, W4, G16, degp, w34g,
                                   embA, esum_ws);
  k_step<0><<<1024, 256, 0, stream>>>(G16, embA, embB, W2, W1, w34g, Xv, degp, esum_ws);
  k_step<0><<<1024, 256, 0, stream>>>(G16, embB, embA, W2, W1, w34g, Xv, degp, esum_ws);
  k_step<1><<<1024, 256, 0, stream>>>(G16, embA, embB, W2, W1, w34g, Xv, degp, esum_ws);
  k_out<<<256, 256, 0, stream>>>(embB, W7, W5, W6, esum_ws, out);
}